// Round 1
// baseline (104.556 us; speedup 1.0000x reference)
//
#include <hip/hip_runtime.h>
#include <stdint.h>

#define NB 4
#define SS 192
#define NI 256

typedef __attribute__((ext_vector_type(8))) short bf16x8;
typedef __attribute__((ext_vector_type(4))) float f32x4;

__device__ __forceinline__ uint16_t f2bf(float f) {
  union { float f; uint32_t u; } v; v.f = f;
  return (uint16_t)((v.u + 0x7FFFu + ((v.u >> 16) & 1u)) >> 16);
}

// multiply two packed bf16 pairs (in a u32), result packed bf16 pair
__device__ __forceinline__ uint32_t bfmul2(uint32_t x, uint32_t y) {
  union { float f; uint32_t u; } xa, xb, ya, yb, r0, r1;
  xa.u = x << 16;        ya.u = y << 16;
  xb.u = x & 0xFFFF0000u; yb.u = y & 0xFFFF0000u;
  r0.f = xa.f * ya.f;
  r1.f = xb.f * yb.f;
  uint32_t lo = (r0.u + 0x7FFFu + ((r0.u >> 16) & 1u)) >> 16;
  uint32_t hi = (r1.u + 0x7FFFu + ((r1.u >> 16) & 1u)) >> 16;
  return lo | (hi << 16);
}

// ---------------- K1: reduce W_tri over (j,k) -> partial sums ----------------
// 1024 blocks, each sums 16384 contiguous floats (4 blocks per i-row).
__global__ void k_wtri_partial(const float* __restrict__ W, float* __restrict__ partial) {
  const int bi = blockIdx.x, tid = threadIdx.x;
  const float4* p = (const float4*)(W + (size_t)bi * 16384);
  float s = 0.f;
  #pragma unroll
  for (int it = 0; it < 16; ++it) {
    float4 v = p[it * 256 + tid];
    s += v.x + v.y + v.z + v.w;
  }
  for (int off = 32; off > 0; off >>= 1) s += __shfl_down(s, off, 64);
  __shared__ float red[4];
  if ((tid & 63) == 0) red[tid >> 6] = s;
  __syncthreads();
  if (tid == 0) partial[bi] = red[0] + red[1] + red[2] + red[3];
}

__global__ void k_wred_finish(const float* __restrict__ partial, float* __restrict__ w_red) {
  const int t = threadIdx.x;
  w_red[t] = partial[4 * t] + partial[4 * t + 1] + partial[4 * t + 2] + partial[4 * t + 3];
}

// ---------------- K2: projections hU = h_head*U, hV = h_head*V, dZ = h_dep*Z ----------------
// grid (96, 3), 256 threads. Block handles 8 rows x 256 cols for one matrix.
__global__ void k_proj(const float* __restrict__ h_head, const float* __restrict__ h_dep,
                       const float* __restrict__ U, const float* __restrict__ V, const float* __restrict__ Z,
                       float* __restrict__ hU, float* __restrict__ hV, float* __restrict__ dZ) {
  const int which = blockIdx.y;
  const int r0 = blockIdx.x * 8;
  const int tid = threadIdx.x;
  const float* A = (which == 2) ? h_dep : h_head;
  const float* M = (which == 0) ? U : (which == 1) ? V : Z;
  float* out = (which == 0) ? hU : (which == 1) ? hV : dZ;
  __shared__ float ah[8][NI];
  #pragma unroll
  for (int r = 0; r < 8; ++r) ah[r][tid] = A[(r0 + r) * NI + tid];
  __syncthreads();
  float acc[8] = {};
  for (int i = 0; i < NI; ++i) {
    float m = M[i * NI + tid];
    #pragma unroll
    for (int r = 0; r < 8; ++r) acc[r] += ah[r][i] * m;
  }
  #pragma unroll
  for (int r = 0; r < 8; ++r) out[(r0 + r) * NI + tid] = acc[r];
}

// ---------------- K2b: bf16 conversions (HW = h_head*w_red, HD, HS) ----------------
__global__ void k_tobf16(const float* __restrict__ h_head, const float* __restrict__ h_dep,
                         const float* __restrict__ h_sib, const float* __restrict__ w_red,
                         uint16_t* __restrict__ HW, uint16_t* __restrict__ HD, uint16_t* __restrict__ HS) {
  const int g = blockIdx.x * 256 + threadIdx.x;
  const float w = w_red[threadIdx.x];   // i == threadIdx.x since NI==256
  HW[g] = f2bf(h_head[g] * w);
  HD[g] = f2bf(h_dep[g]);
  HS[g] = f2bf(h_sib[g]);
}

// ---------------- K3: biaffine score matrices ----------------
// grid (24, 4, 3): (x-tile of 8, b, which). 192 threads = y index.
__global__ void k_scores(const float* __restrict__ hU, const float* __restrict__ hV, const float* __restrict__ dZ,
                         const float* __restrict__ h_dep, const float* __restrict__ h_sib,
                         float* __restrict__ s_hd, float* __restrict__ s_hs, float* __restrict__ s_ds) {
  const int which = blockIdx.z, b = blockIdx.y, x0 = blockIdx.x * 8;
  const int tid = threadIdx.x; // 0..191
  const float* A = (which == 0) ? hU : (which == 1) ? hV : dZ;
  const float* B = (which == 0) ? h_dep : h_sib;
  float* out = (which == 0) ? s_hd : (which == 1) ? s_hs : s_ds;
  __shared__ float ar[8][NI];
  for (int idx = tid; idx < 8 * NI; idx += 192)
    ar[idx >> 8][idx & 255] = A[(b * SS + x0 + (idx >> 8)) * NI + (idx & 255)];
  __syncthreads();
  const float4* bp = (const float4*)(B + (b * SS + tid) * NI);
  float acc[8] = {};
  for (int c = 0; c < NI / 4; ++c) {
    float4 bv = bp[c];
    #pragma unroll
    for (int r = 0; r < 8; ++r) {
      float4 av = ((const float4*)ar[r])[c];
      acc[r] += av.x * bv.x + av.y * bv.y + av.z * bv.z + av.w * bv.w;
    }
  }
  #pragma unroll
  for (int r = 0; r < 8; ++r) out[(b * SS + x0 + r) * SS + tid] = acc[r];
}

// ---------------- K4: main fused GEMM + epilogue ----------------
// grid (9, 192, 4) = (d/s tile, h, b). 256 threads = 4 waves in 2x2 over a 64x64 tile.
// out[b,h,d,s] = sum_i HW[bh,i]*HD[bd,i]*HS[bs,i] + s_hd + s_hs + s_ds + bias
__global__ __launch_bounds__(256, 2) void k_big(
    const uint16_t* __restrict__ HW, const uint16_t* __restrict__ HD, const uint16_t* __restrict__ HS,
    const float* __restrict__ s_hd, const float* __restrict__ s_hs, const float* __restrict__ s_ds,
    const float* __restrict__ bias, float* __restrict__ out) {
  __shared__ __align__(16) unsigned char lds[65536];  // A-tile [64][256] bf16 @0, B-tile @32768
  const int tile = blockIdx.x;
  const int h = blockIdx.y, b = blockIdx.z;
  const int d0 = (tile / 3) * 64, s0 = (tile % 3) * 64;
  const int tid = threadIdx.x;
  const int bh = b * SS + h;

  // ---- stage A = bf16(HW ⊙ HD-rows), B = HS-rows, XOR-swizzled ----
  const uint16_t* hwrow = HW + bh * NI;
  #pragma unroll
  for (int it = 0; it < 8; ++it) {
    const int c = it * 256 + tid;          // chunk of 8 bf16; 2048 chunks total
    const int row = c >> 5, col8 = c & 31;
    const int col = col8 * 8;
    uint4 hd4 = *(const uint4*)(HD + ((b * SS + d0 + row) * NI + col));
    uint4 hw4 = *(const uint4*)(hwrow + col);
    uint4 a4;
    a4.x = bfmul2(hd4.x, hw4.x);
    a4.y = bfmul2(hd4.y, hw4.y);
    a4.z = bfmul2(hd4.z, hw4.z);
    a4.w = bfmul2(hd4.w, hw4.w);
    const int byteA = (row << 9) | (col8 << 4);
    const int swz = byteA ^ ((row & 7) << 4);
    *(uint4*)(lds + swz) = a4;
    uint4 hs4 = *(const uint4*)(HS + ((b * SS + s0 + row) * NI + col));
    *(uint4*)(lds + 32768 + swz) = hs4;
  }
  __syncthreads();

  // ---- MFMA over K=256 in 8 steps ----
  const int lane = tid & 63, w = tid >> 6;
  const int m0 = (w >> 1) * 32, n0 = (w & 1) * 32;
  const int fr = lane & 15;            // A-row / B-col within fragment
  const int kb = (lane >> 4) * 8;      // k base within 32-step
  f32x4 acc[2][2] = {};
  #pragma unroll
  for (int ks = 0; ks < 8; ++ks) {
    const int k2 = (ks * 32 + kb) * 2; // byte offset of k within a row
    bf16x8 a[2], bb[2];
    #pragma unroll
    for (int mt = 0; mt < 2; ++mt) {
      const int r = m0 + mt * 16 + fr;
      const int off = ((r << 9) + k2) ^ ((r & 7) << 4);
      a[mt] = *reinterpret_cast<const bf16x8*>(lds + off);
    }
    #pragma unroll
    for (int nt = 0; nt < 2; ++nt) {
      const int r = n0 + nt * 16 + fr;
      const int off = ((r << 9) + k2) ^ ((r & 7) << 4);
      bb[nt] = *reinterpret_cast<const bf16x8*>(lds + 32768 + off);
    }
    #pragma unroll
    for (int mt = 0; mt < 2; ++mt)
      #pragma unroll
      for (int nt = 0; nt < 2; ++nt)
        acc[mt][nt] = __builtin_amdgcn_mfma_f32_16x16x32_bf16(a[mt], bb[nt], acc[mt][nt], 0, 0, 0);
  }

  // ---- epilogue: add s_hd + s_hs + s_ds + bias, write f32 ----
  const float bias0 = bias[0];
  #pragma unroll
  for (int mt = 0; mt < 2; ++mt) {
    #pragma unroll
    for (int j = 0; j < 4; ++j) {
      const int d = d0 + m0 + mt * 16 + (lane >> 4) * 4 + j;
      const float add_hd = s_hd[bh * SS + d] + bias0;
      #pragma unroll
      for (int nt = 0; nt < 2; ++nt) {
        const int s = s0 + n0 + nt * 16 + fr;
        const float v = acc[mt][nt][j] + add_hd + s_hs[bh * SS + s] + s_ds[(b * SS + d) * SS + s];
        out[(size_t)(bh * SS + d) * SS + s] = v;
      }
    }
  }
}

extern "C" void kernel_launch(void* const* d_in, const int* in_sizes, int n_in,
                              void* d_out, int out_size, void* d_ws, size_t ws_size,
                              hipStream_t stream) {
  const float* h_head = (const float*)d_in[0];
  const float* h_dep  = (const float*)d_in[1];
  const float* h_sib  = (const float*)d_in[2];
  const float* W_tri  = (const float*)d_in[3];
  const float* U_hd   = (const float*)d_in[4];
  const float* V_hs   = (const float*)d_in[5];
  const float* Z_ds   = (const float*)d_in[6];
  const float* bias   = (const float*)d_in[7];
  float* out = (float*)d_out;

  // workspace carve-up (~5.1 MB total)
  float* w_red   = (float*)d_ws;              // 256
  float* partial = w_red + 256;               // 1024
  float* hU      = partial + 1024;            // 768*256
  float* hV      = hU + 768 * NI;
  float* dZ      = hV + 768 * NI;
  float* s_hd    = dZ + 768 * NI;             // 4*192*192
  float* s_hs    = s_hd + NB * SS * SS;
  float* s_ds    = s_hs + NB * SS * SS;
  uint16_t* HW   = (uint16_t*)(s_ds + NB * SS * SS);  // 768*256 bf16
  uint16_t* HD   = HW + 768 * NI;
  uint16_t* HS   = HD + 768 * NI;

  k_wtri_partial<<<1024, 256, 0, stream>>>(W_tri, partial);
  k_wred_finish<<<1, 256, 0, stream>>>(partial, w_red);
  k_proj<<<dim3(96, 3), 256, 0, stream>>>(h_head, h_dep, U_hd, V_hs, Z_ds, hU, hV, dZ);
  k_tobf16<<<768, 256, 0, stream>>>(h_head, h_dep, h_sib, w_red, HW, HD, HS);
  k_scores<<<dim3(24, 4, 3), 192, 0, stream>>>(hU, hV, dZ, h_dep, h_sib, s_hd, s_hs, s_ds);
  k_big<<<dim3(9, SS, NB), 256, 0, stream>>>(HW, HD, HS, s_hd, s_hs, s_ds, bias, out);
}